// Round 2
// baseline (1121.800 us; speedup 1.0000x reference)
//
#include <hip/hip_runtime.h>
#include <hip/hip_bf16.h>
#include <cstdint>
#include <cstddef>

#define BB 2
#define TT 2048
#define DD 2048
#define NH 16
#define NKV 4
#define HD 128
#define NI 8192
#define MM (BB*TT)

typedef __bf16 bf16x8 __attribute__((ext_vector_type(8)));
typedef float  f32x4  __attribute__((ext_vector_type(4)));

__device__ __forceinline__ void gload_lds16(const void* g, void* l) {
  __builtin_amdgcn_global_load_lds((__attribute__((address_space(1))) void*)g,
                                   (__attribute__((address_space(3))) void*)l,
                                   16, 0, 0);
}

// ---------------- RoPE tables: cos/sin[pos][d], pos<4096, d<128 ----------------
__global__ __launch_bounds__(128) void rope_tables_k(float* __restrict__ cosT,
                                                     float* __restrict__ sinT) {
  int pos = blockIdx.x;
  int d = threadIdx.x;
  int f = d & 63;
  float inv = powf(10000.0f, -((float)(2 * f)) / 128.0f);
  float ang = inv * (float)pos;
  cosT[pos * 128 + d] = cosf(ang);
  sinT[pos * 128 + d] = sinf(ang);
}

// ---------------- transpose + convert to bf16: in[R][C] -> out[C][R] ----------------
template <typename TIN>
__global__ __launch_bounds__(256) void transpose_to_bf16_k(const TIN* __restrict__ in,
                                                           __bf16* __restrict__ out,
                                                           int R, int C) {
  __shared__ float t[32][33];
  int c0 = blockIdx.x * 32, r0 = blockIdx.y * 32;
  int tx = threadIdx.x & 31;
  int ty = threadIdx.x >> 5;  // 0..7
#pragma unroll
  for (int i = 0; i < 4; i++) {
    int r = ty + i * 8;
    t[r][tx] = (float)in[(size_t)(r0 + r) * C + c0 + tx];
  }
  __syncthreads();
#pragma unroll
  for (int i = 0; i < 4; i++) {
    int r = ty + i * 8;
    out[(size_t)(c0 + r) * R + r0 + tx] = (__bf16)t[tx][r];
  }
}

// ---------------- RMSNorm: f32 in -> bf16 out (one row per block, D=2048) ----------------
__global__ __launch_bounds__(256) void rmsnorm_k(const float* __restrict__ x,
                                                 const float* __restrict__ w,
                                                 __bf16* __restrict__ out) {
  int row = blockIdx.x;
  const float* xr = x + (size_t)row * DD;
  int t = threadIdx.x;
  float4 a = ((const float4*)xr)[2 * t];
  float4 b = ((const float4*)xr)[2 * t + 1];
  float ss = a.x * a.x + a.y * a.y + a.z * a.z + a.w * a.w +
             b.x * b.x + b.y * b.y + b.z * b.z + b.w * b.w;
#pragma unroll
  for (int off = 32; off; off >>= 1) ss += __shfl_xor(ss, off, 64);
  __shared__ float red[4];
  if ((t & 63) == 0) red[t >> 6] = ss;
  __syncthreads();
  float tot = red[0] + red[1] + red[2] + red[3];
  float rs = rsqrtf(tot * (1.0f / DD) + 1e-6f);
  const float4 w1 = ((const float4*)w)[2 * t];
  const float4 w2 = ((const float4*)w)[2 * t + 1];
  bf16x8 ov;
  ov[0] = (__bf16)(a.x * rs * w1.x);
  ov[1] = (__bf16)(a.y * rs * w1.y);
  ov[2] = (__bf16)(a.z * rs * w1.z);
  ov[3] = (__bf16)(a.w * rs * w1.w);
  ov[4] = (__bf16)(b.x * rs * w2.x);
  ov[5] = (__bf16)(b.y * rs * w2.y);
  ov[6] = (__bf16)(b.z * rs * w2.z);
  ov[7] = (__bf16)(b.w * rs * w2.w);
  *(bf16x8*)(out + (size_t)row * DD + t * 8) = ov;
}

// ---------------- GEMM: C[M,N] = A[M,K] * Bt[N,K]^T, 128x128 tile, BK=32 ----------------
enum { EPI_BF16 = 0, EPI_ROPE = 1, EPI_SIG = 2, EPI_RES = 3, EPI_SILU = 4 };

template <int EPI>
__global__ __launch_bounds__(256) void gemm_k(
    const __bf16* __restrict__ A, const __bf16* __restrict__ Bt,
    __bf16* __restrict__ outB, float* __restrict__ outF,
    const float* __restrict__ bias, const float* __restrict__ residual,
    const float* __restrict__ cosT, const float* __restrict__ sinT,
    const int* __restrict__ posids, int N, int K) {
  __shared__ __align__(16) __bf16 As[128 * 32];
  __shared__ __align__(16) __bf16 Bs[128 * 32];
  const int tid = threadIdx.x;
  const int lane = tid & 63;
  const int w = tid >> 6;
  const int wm = w >> 1, wn = w & 1;
  const int m0 = blockIdx.y * 128;
  const int n0 = blockIdx.x * 128;

  const int lr = lane >> 2;
  const int lc = (lane & 3) * 8;
  const __bf16* aSrc = A + (size_t)(m0 + 32 * w + lr) * K + lc;
  const __bf16* bSrc = Bt + (size_t)(n0 + 32 * w + lr) * K + lc;
  __bf16* aDst = &As[w * 1024];
  __bf16* bDst = &Bs[w * 1024];

  f32x4 acc[4][4];
#pragma unroll
  for (int i = 0; i < 4; i++)
#pragma unroll
    for (int j = 0; j < 4; j++) acc[i][j] = (f32x4){0.f, 0.f, 0.f, 0.f};

  const int fr = lane & 15;
  const int fc = (lane >> 4) * 8;

  for (int k0 = 0; k0 < K; k0 += 32) {
    __syncthreads();
    gload_lds16(aSrc + k0, aDst);
    gload_lds16(aSrc + k0 + (size_t)16 * K, aDst + 512);
    gload_lds16(bSrc + k0, bDst);
    gload_lds16(bSrc + k0 + (size_t)16 * K, bDst + 512);
    asm volatile("s_waitcnt vmcnt(0)" ::: "memory");
    __syncthreads();

    bf16x8 af[4], bfg[4];
#pragma unroll
    for (int i = 0; i < 4; i++)
      af[i] = *(const bf16x8*)&As[(wm * 64 + i * 16 + fr) * 32 + fc];
#pragma unroll
    for (int i = 0; i < 4; i++)
      bfg[i] = *(const bf16x8*)&Bs[(wn * 64 + i * 16 + fr) * 32 + fc];
#pragma unroll
    for (int mi = 0; mi < 4; mi++)
#pragma unroll
      for (int ni = 0; ni < 4; ni++)
        acc[mi][ni] =
            __builtin_amdgcn_mfma_f32_16x16x32_bf16(af[mi], bfg[ni], acc[mi][ni], 0, 0, 0);
  }

  const int fg = lane >> 4;
#pragma unroll
  for (int mi = 0; mi < 4; mi++) {
#pragma unroll
    for (int ni = 0; ni < 4; ni++) {
#pragma unroll
      for (int j = 0; j < 4; j++) {
        int row = m0 + wm * 64 + mi * 16 + fg * 4 + j;
        int col = n0 + wn * 64 + ni * 16 + fr;
        float v = acc[mi][ni][j];
        if constexpr (EPI == EPI_BF16) {
          outB[(size_t)row * N + col] = (__bf16)v;
        } else if constexpr (EPI == EPI_ROPE) {
          float vp = __shfl_xor(v, 1, 64);
          int pos = posids[row];
          int d = col & 127;
          float c = cosT[pos * 128 + d];
          float s = sinT[pos * 128 + d];
          float o = (col & 1) ? (v * c + vp * s) : (v * c - vp * s);
          outB[(size_t)row * N + col] = (__bf16)o;
        } else if constexpr (EPI == EPI_SIG) {
          float xx = v + bias[col];
          outB[(size_t)row * N + col] = (__bf16)(1.0f / (1.0f + expf(-xx)));
        } else if constexpr (EPI == EPI_RES) {
          outF[(size_t)row * N + col] = v + residual[(size_t)row * N + col];
        } else if constexpr (EPI == EPI_SILU) {
          outB[(size_t)row * N + col] = (__bf16)(v / (1.0f + expf(-v)));
        }
      }
    }
  }
}

// ---------------- Flash attention, causal, GQA 16/4, D=128 ----------------
__global__ __launch_bounds__(256) void attn_k(const __bf16* __restrict__ Q,
                                              const __bf16* __restrict__ Kb,
                                              const __bf16* __restrict__ Vt,
                                              const __bf16* __restrict__ Gate,
                                              __bf16* __restrict__ Out) {
  __shared__ __align__(16) __bf16 Ks[32 * 128];   // [kv][d]
  __shared__ __align__(16) __bf16 Vs[128 * 32];   // [d][kv]
  __shared__ __align__(16) __bf16 Ps[4][16 * 32]; // per-wave [q][kv]
  const int tid = threadIdx.x;
  const int lane = tid & 63;
  const int w = tid >> 6;
  const int q0 = blockIdx.x * 64;
  const int bh = blockIdx.y;
  const int b = bh >> 4, h = bh & 15;
  const int g = h >> 2;
  const int fr = lane & 15;
  const int fg = lane >> 4;

  const size_t qrow = (size_t)(b * TT + q0 + w * 16 + fr);
  bf16x8 qf[4];
#pragma unroll
  for (int kt = 0; kt < 4; kt++)
    qf[kt] = *(const bf16x8*)&Q[qrow * 2048 + h * 128 + kt * 32 + fg * 8];

  f32x4 o[8];
#pragma unroll
  for (int i = 0; i < 8; i++) o[i] = (f32x4){0.f, 0.f, 0.f, 0.f};
  float mrow[4] = {-3e38f, -3e38f, -3e38f, -3e38f};
  float lrow[4] = {0.f, 0.f, 0.f, 0.f};

  const int qmax = q0 + w * 16 + 15;
  const int kend = q0 + 64;

  const __bf16* kSrc = Kb + (size_t)(b * TT + 8 * w + (lane >> 4)) * 512 + g * 128 + (lane & 15) * 8;
  const __bf16* vSrc = Vt + (size_t)(g * 128 + 32 * w + (lane >> 2)) * (size_t)MM + b * TT + (lane & 3) * 8;

  for (int kb = 0; kb < kend; kb += 32) {
    __syncthreads();
    gload_lds16(kSrc + (size_t)kb * 512, &Ks[w * 1024]);
    gload_lds16(kSrc + (size_t)kb * 512 + 4 * 512, &Ks[w * 1024 + 512]);
    gload_lds16(vSrc + kb, &Vs[w * 1024]);
    gload_lds16(vSrc + kb + (size_t)16 * MM, &Vs[w * 1024 + 512]);
    asm volatile("s_waitcnt vmcnt(0)" ::: "memory");
    __syncthreads();

    if (kb <= qmax) {
      f32x4 s[2];
      s[0] = (f32x4){0.f, 0.f, 0.f, 0.f};
      s[1] = (f32x4){0.f, 0.f, 0.f, 0.f};
#pragma unroll
      for (int nc = 0; nc < 2; nc++)
#pragma unroll
        for (int kt = 0; kt < 4; kt++) {
          bf16x8 kf = *(const bf16x8*)&Ks[(nc * 16 + fr) * 128 + kt * 32 + fg * 8];
          s[nc] = __builtin_amdgcn_mfma_f32_16x16x32_bf16(qf[kt], kf, s[nc], 0, 0, 0);
        }
      const float sc = 0.08838834764831845f;  // 1/sqrt(128)
      float p[2][4];
      float alpha[4];
#pragma unroll
      for (int j = 0; j < 4; j++) {
        int qr = q0 + w * 16 + fg * 4 + j;
#pragma unroll
        for (int nc = 0; nc < 2; nc++) {
          int kc = kb + nc * 16 + fr;
          float val = s[nc][j] * sc;
          if (kc > qr) val = -1e9f;
          p[nc][j] = val;
        }
        float tmx = fmaxf(p[0][j], p[1][j]);
        tmx = fmaxf(tmx, __shfl_xor(tmx, 1, 64));
        tmx = fmaxf(tmx, __shfl_xor(tmx, 2, 64));
        tmx = fmaxf(tmx, __shfl_xor(tmx, 4, 64));
        tmx = fmaxf(tmx, __shfl_xor(tmx, 8, 64));
        float mnew = fmaxf(mrow[j], tmx);
        alpha[j] = expf(mrow[j] - mnew);
        mrow[j] = mnew;
        p[0][j] = expf(p[0][j] - mnew);
        p[1][j] = expf(p[1][j] - mnew);
        float rsum = p[0][j] + p[1][j];
        rsum += __shfl_xor(rsum, 1, 64);
        rsum += __shfl_xor(rsum, 2, 64);
        rsum += __shfl_xor(rsum, 4, 64);
        rsum += __shfl_xor(rsum, 8, 64);
        lrow[j] = lrow[j] * alpha[j] + rsum;
      }
#pragma unroll
      for (int nd = 0; nd < 8; nd++)
#pragma unroll
        for (int j = 0; j < 4; j++) o[nd][j] *= alpha[j];
#pragma unroll
      for (int j = 0; j < 4; j++)
#pragma unroll
        for (int nc = 0; nc < 2; nc++)
          Ps[w][(fg * 4 + j) * 32 + nc * 16 + fr] = (__bf16)p[nc][j];
      bf16x8 pa = *(const bf16x8*)&Ps[w][fr * 32 + fg * 8];
#pragma unroll
      for (int nd = 0; nd < 8; nd++) {
        bf16x8 vf = *(const bf16x8*)&Vs[(nd * 16 + fr) * 32 + fg * 8];
        o[nd] = __builtin_amdgcn_mfma_f32_16x16x32_bf16(pa, vf, o[nd], 0, 0, 0);
      }
    }
  }

  float invl[4];
#pragma unroll
  for (int j = 0; j < 4; j++) invl[j] = 1.0f / lrow[j];
#pragma unroll
  for (int nd = 0; nd < 8; nd++) {
#pragma unroll
    for (int j = 0; j < 4; j++) {
      int row = q0 + w * 16 + fg * 4 + j;
      int d = nd * 16 + fr;
      size_t idx = (size_t)(b * TT + row) * 2048 + h * 128 + d;
      float val = o[nd][j] * invl[j] * (float)Gate[idx];
      Out[idx] = (__bf16)val;
    }
  }
}

// ---------------- host ----------------
extern "C" void kernel_launch(void* const* d_in, const int* in_sizes, int n_in,
                              void* d_out, int out_size, void* d_ws, size_t ws_size,
                              hipStream_t stream) {
  const float* hidden = (const float*)d_in[0];
  const int* posids = (const int*)d_in[2];
  const float* attn_w = (const float*)d_in[3];
  const float* mlp_w = (const float*)d_in[4];
  const float* wq = (const float*)d_in[5];
  const float* wk = (const float*)d_in[6];
  const float* wv = (const float*)d_in[7];
  const float* wo = (const float*)d_in[8];
  const float* gw = (const float*)d_in[9];
  const float* gb = (const float*)d_in[10];
  const float* f1 = (const float*)d_in[11];
  const float* f2 = (const float*)d_in[12];

  char* p = (char*)d_ws;
  auto alloc = [&](size_t n) {
    char* r = p;
    p += (n + 255) & ~(size_t)255;
    return r;
  };
  // --- persistent (live across the whole launch): 92 + 16 + 32 MiB ---
  __bf16* wq_t = (__bf16*)alloc((size_t)2048 * 2048 * 2);   // 8 MiB
  __bf16* wk_t = (__bf16*)alloc((size_t)512 * 2048 * 2);    // 2 MiB
  __bf16* wv_t = (__bf16*)alloc((size_t)512 * 2048 * 2);    // 2 MiB
  __bf16* gw_t = (__bf16*)alloc((size_t)2048 * 2048 * 2);   // 8 MiB
  __bf16* wo_t = (__bf16*)alloc((size_t)2048 * 2048 * 2);   // 8 MiB
  __bf16* f1_t = (__bf16*)alloc((size_t)NI * 2048 * 2);     // 32 MiB
  __bf16* f2_t = (__bf16*)alloc((size_t)2048 * NI * 2);     // 32 MiB
  __bf16* h_bf = (__bf16*)alloc((size_t)MM * DD * 2);       // 16 MiB (h, then h2)
  float* h1 = (float*)alloc((size_t)MM * 2048 * 4);         // 32 MiB

  // --- union region: attention intermediates (64 MiB) then mlp1 (64 MiB) ---
  char* regionA = alloc((size_t)64 * 1024 * 1024);
  __bf16* q_bf    = (__bf16*)(regionA);                               // 16 MiB
  __bf16* gate_bf = (__bf16*)(regionA + (size_t)16 * 1024 * 1024);    // 16 MiB
  __bf16* attn_g  = (__bf16*)(regionA + (size_t)32 * 1024 * 1024);    // 16 MiB
  __bf16* k_bf    = (__bf16*)(regionA + (size_t)48 * 1024 * 1024);    // 4 MiB
  __bf16* v_bf    = (__bf16*)(regionA + (size_t)52 * 1024 * 1024);    // 4 MiB
  __bf16* v_t     = (__bf16*)(regionA + (size_t)56 * 1024 * 1024);    // 4 MiB
  float*  cosT    = (float*)(regionA + (size_t)60 * 1024 * 1024);     // 2 MiB
  float*  sinT    = (float*)(regionA + (size_t)62 * 1024 * 1024);     // 2 MiB
  __bf16* mlp1    = (__bf16*)(regionA);  // 64 MiB, written after all of the above die

  // RoPE tables
  rope_tables_k<<<4096, 128, 0, stream>>>(cosT, sinT);

  // weight transposes (f32 [K][N] -> bf16 [N][K])
  transpose_to_bf16_k<float><<<dim3(2048 / 32, 2048 / 32), 256, 0, stream>>>(wq, wq_t, 2048, 2048);
  transpose_to_bf16_k<float><<<dim3(512 / 32, 2048 / 32), 256, 0, stream>>>(wk, wk_t, 2048, 512);
  transpose_to_bf16_k<float><<<dim3(512 / 32, 2048 / 32), 256, 0, stream>>>(wv, wv_t, 2048, 512);
  transpose_to_bf16_k<float><<<dim3(2048 / 32, 2048 / 32), 256, 0, stream>>>(gw, gw_t, 2048, 2048);
  transpose_to_bf16_k<float><<<dim3(2048 / 32, 2048 / 32), 256, 0, stream>>>(wo, wo_t, 2048, 2048);
  transpose_to_bf16_k<float><<<dim3(NI / 32, 2048 / 32), 256, 0, stream>>>(f1, f1_t, 2048, NI);
  transpose_to_bf16_k<float><<<dim3(2048 / 32, NI / 32), 256, 0, stream>>>(f2, f2_t, NI, 2048);

  // attn RMSNorm
  rmsnorm_k<<<MM, 256, 0, stream>>>(hidden, attn_w, h_bf);

  // projections
  gemm_k<EPI_ROPE><<<dim3(16, 32), 256, 0, stream>>>(h_bf, wq_t, q_bf, nullptr, nullptr,
                                                     nullptr, cosT, sinT, posids, 2048, 2048);
  gemm_k<EPI_ROPE><<<dim3(4, 32), 256, 0, stream>>>(h_bf, wk_t, k_bf, nullptr, nullptr,
                                                    nullptr, cosT, sinT, posids, 512, 2048);
  gemm_k<EPI_BF16><<<dim3(4, 32), 256, 0, stream>>>(h_bf, wv_t, v_bf, nullptr, nullptr,
                                                    nullptr, nullptr, nullptr, nullptr, 512, 2048);
  gemm_k<EPI_SIG><<<dim3(16, 32), 256, 0, stream>>>(h_bf, gw_t, gate_bf, nullptr, gb,
                                                    nullptr, nullptr, nullptr, nullptr, 2048, 2048);

  // V transpose: [4096][512] -> [512][4096]
  transpose_to_bf16_k<__bf16><<<dim3(512 / 32, MM / 32), 256, 0, stream>>>(v_bf, v_t, MM, 512);

  // attention (+gate fused)
  attn_k<<<dim3(TT / 64, BB * NH), 256, 0, stream>>>(q_bf, k_bf, v_t, gate_bf, attn_g);

  // wo projection + residual -> h1 (f32)
  gemm_k<EPI_RES><<<dim3(16, 32), 256, 0, stream>>>(attn_g, wo_t, nullptr, h1, nullptr,
                                                    hidden, nullptr, nullptr, nullptr, 2048, 2048);

  // mlp RMSNorm (h2 reuses h_bf slot)
  rmsnorm_k<<<MM, 256, 0, stream>>>(h1, mlp_w, h_bf);

  // fc1 + SiLU  (mlp1 overlays the dead attention intermediates)
  gemm_k<EPI_SILU><<<dim3(NI / 128, 32), 256, 0, stream>>>(h_bf, f1_t, mlp1, nullptr, nullptr,
                                                           nullptr, nullptr, nullptr, nullptr, NI, 2048);

  // fc2 + residual -> d_out (f32)
  gemm_k<EPI_RES><<<dim3(16, 32), 256, 0, stream>>>(mlp1, f2_t, nullptr, (float*)d_out, nullptr,
                                                    h1, nullptr, nullptr, nullptr, 2048, NI);
}

// Round 3
// 904.298 us; speedup vs baseline: 1.2405x; 1.2405x over previous
//
#include <hip/hip_runtime.h>
#include <hip/hip_bf16.h>
#include <cstdint>
#include <cstddef>

#define BB 2
#define TT 2048
#define DD 2048
#define NH 16
#define NKV 4
#define HD 128
#define NI 8192
#define MM (BB*TT)

typedef __bf16 bf16x8 __attribute__((ext_vector_type(8)));
typedef float  f32x4  __attribute__((ext_vector_type(4)));

__device__ __forceinline__ void gload_lds16(const void* g, void* l) {
  __builtin_amdgcn_global_load_lds((__attribute__((address_space(1))) void*)g,
                                   (__attribute__((address_space(3))) void*)l,
                                   16, 0, 0);
}

// bijective XCD swizzle (m204): contiguous chunks of original order per XCD
__device__ __forceinline__ int xcd_swizzle(int wg, int nwg) {
  int xcd = wg & 7;
  int l = wg >> 3;
  int q = nwg >> 3, r = nwg & 7;
  return (xcd < r ? xcd * (q + 1) : r * (q + 1) + (xcd - r) * q) + l;
}

// ---------------- RoPE tables ----------------
__global__ __launch_bounds__(128) void rope_tables_k(float* __restrict__ cosT,
                                                     float* __restrict__ sinT) {
  int pos = blockIdx.x;
  int d = threadIdx.x;
  int f = d & 63;
  float inv = powf(10000.0f, -((float)(2 * f)) / 128.0f);
  float ang = inv * (float)pos;
  cosT[pos * 128 + d] = cosf(ang);
  sinT[pos * 128 + d] = sinf(ang);
}

// ---------------- transpose + convert to bf16 ----------------
template <typename TIN>
__global__ __launch_bounds__(256) void transpose_to_bf16_k(const TIN* __restrict__ in,
                                                           __bf16* __restrict__ out,
                                                           int R, int C) {
  __shared__ float t[32][33];
  int c0 = blockIdx.x * 32, r0 = blockIdx.y * 32;
  int tx = threadIdx.x & 31;
  int ty = threadIdx.x >> 5;
#pragma unroll
  for (int i = 0; i < 4; i++) {
    int r = ty + i * 8;
    t[r][tx] = (float)in[(size_t)(r0 + r) * C + c0 + tx];
  }
  __syncthreads();
#pragma unroll
  for (int i = 0; i < 4; i++) {
    int r = ty + i * 8;
    out[(size_t)(c0 + r) * R + r0 + tx] = (__bf16)t[tx][r];
  }
}

// ---------------- RMSNorm ----------------
__global__ __launch_bounds__(256) void rmsnorm_k(const float* __restrict__ x,
                                                 const float* __restrict__ w,
                                                 __bf16* __restrict__ out) {
  int row = blockIdx.x;
  const float* xr = x + (size_t)row * DD;
  int t = threadIdx.x;
  float4 a = ((const float4*)xr)[2 * t];
  float4 b = ((const float4*)xr)[2 * t + 1];
  float ss = a.x * a.x + a.y * a.y + a.z * a.z + a.w * a.w +
             b.x * b.x + b.y * b.y + b.z * b.z + b.w * b.w;
#pragma unroll
  for (int off = 32; off; off >>= 1) ss += __shfl_xor(ss, off, 64);
  __shared__ float red[4];
  if ((t & 63) == 0) red[t >> 6] = ss;
  __syncthreads();
  float tot = red[0] + red[1] + red[2] + red[3];
  float rs = rsqrtf(tot * (1.0f / DD) + 1e-6f);
  const float4 w1 = ((const float4*)w)[2 * t];
  const float4 w2 = ((const float4*)w)[2 * t + 1];
  bf16x8 ov;
  ov[0] = (__bf16)(a.x * rs * w1.x);
  ov[1] = (__bf16)(a.y * rs * w1.y);
  ov[2] = (__bf16)(a.z * rs * w1.z);
  ov[3] = (__bf16)(a.w * rs * w1.w);
  ov[4] = (__bf16)(b.x * rs * w2.x);
  ov[5] = (__bf16)(b.y * rs * w2.y);
  ov[6] = (__bf16)(b.z * rs * w2.z);
  ov[7] = (__bf16)(b.w * rs * w2.w);
  *(bf16x8*)(out + (size_t)row * DD + t * 8) = ov;
}

// ---------------- GEMM 128x128, BK=32 ----------------
enum { EPI_BF16 = 0, EPI_ROPE = 1, EPI_SIG = 2, EPI_RES = 3, EPI_SILU = 4 };

template <int EPI>
__global__ __launch_bounds__(256) void gemm_k(
    const __bf16* __restrict__ A, const __bf16* __restrict__ Bt,
    __bf16* __restrict__ outB, float* __restrict__ outF,
    const float* __restrict__ bias, const float* __restrict__ residual,
    const float* __restrict__ cosT, const float* __restrict__ sinT,
    const int* __restrict__ posids, int N, int K, float oscale) {
  __shared__ __align__(16) __bf16 As[128 * 32];
  __shared__ __align__(16) __bf16 Bs[128 * 32];
  const int tid = threadIdx.x;
  const int lane = tid & 63;
  const int w = tid >> 6;
  const int wm = w >> 1, wn = w & 1;

  const int nwg = gridDim.x * gridDim.y;
  int wg = xcd_swizzle(blockIdx.y * gridDim.x + blockIdx.x, nwg);
  const int bx = wg % gridDim.x, by = wg / gridDim.x;
  const int m0 = by * 128;
  const int n0 = bx * 128;

  const int lr = lane >> 2;
  const int lc = (lane & 3) * 8;
  const __bf16* aSrc = A + (size_t)(m0 + 32 * w + lr) * K + lc;
  const __bf16* bSrc = Bt + (size_t)(n0 + 32 * w + lr) * K + lc;
  __bf16* aDst = &As[w * 1024];
  __bf16* bDst = &Bs[w * 1024];

  f32x4 acc[4][4];
#pragma unroll
  for (int i = 0; i < 4; i++)
#pragma unroll
    for (int j = 0; j < 4; j++) acc[i][j] = (f32x4){0.f, 0.f, 0.f, 0.f};

  const int fr = lane & 15;
  const int fc = (lane >> 4) * 8;

  for (int k0 = 0; k0 < K; k0 += 32) {
    __syncthreads();
    gload_lds16(aSrc + k0, aDst);
    gload_lds16(aSrc + k0 + (size_t)16 * K, aDst + 512);
    gload_lds16(bSrc + k0, bDst);
    gload_lds16(bSrc + k0 + (size_t)16 * K, bDst + 512);
    asm volatile("s_waitcnt vmcnt(0)" ::: "memory");
    __syncthreads();

    bf16x8 af[4], bfg[4];
#pragma unroll
    for (int i = 0; i < 4; i++)
      af[i] = *(const bf16x8*)&As[(wm * 64 + i * 16 + fr) * 32 + fc];
#pragma unroll
    for (int i = 0; i < 4; i++)
      bfg[i] = *(const bf16x8*)&Bs[(wn * 64 + i * 16 + fr) * 32 + fc];
#pragma unroll
    for (int mi = 0; mi < 4; mi++)
#pragma unroll
      for (int ni = 0; ni < 4; ni++)
        acc[mi][ni] =
            __builtin_amdgcn_mfma_f32_16x16x32_bf16(af[mi], bfg[ni], acc[mi][ni], 0, 0, 0);
  }

  const int fg = lane >> 4;
#pragma unroll
  for (int mi = 0; mi < 4; mi++) {
#pragma unroll
    for (int ni = 0; ni < 4; ni++) {
#pragma unroll
      for (int j = 0; j < 4; j++) {
        int row = m0 + wm * 64 + mi * 16 + fg * 4 + j;
        int col = n0 + wn * 64 + ni * 16 + fr;
        float v = acc[mi][ni][j];
        if constexpr (EPI == EPI_BF16) {
          outB[(size_t)row * N + col] = (__bf16)v;
        } else if constexpr (EPI == EPI_ROPE) {
          float vp = __shfl_xor(v, 1, 64);
          int pos = posids[row];
          int d = col & 127;
          float c = cosT[pos * 128 + d];
          float s = sinT[pos * 128 + d];
          float o = (col & 1) ? (v * c + vp * s) : (v * c - vp * s);
          outB[(size_t)row * N + col] = (__bf16)(o * oscale);
        } else if constexpr (EPI == EPI_SIG) {
          float xx = v + bias[col];
          outB[(size_t)row * N + col] = (__bf16)(1.0f / (1.0f + expf(-xx)));
        } else if constexpr (EPI == EPI_RES) {
          outF[(size_t)row * N + col] = v + residual[(size_t)row * N + col];
        } else if constexpr (EPI == EPI_SILU) {
          outB[(size_t)row * N + col] = (__bf16)(v / (1.0f + expf(-v)));
        }
      }
    }
  }
}

// ---------------- Flash attention v2: KVBLK=64, swizzled LDS, double-buffered ----------------
// Q pre-scaled by 1/sqrt(128). K LDS: (r,c)->r*128 + (((c>>3)^(r&15))<<3) + (c&7)
// V LDS: (d,kv)->d*64 + (((kv>>3)^(d&7))<<3) + (kv&7)
// P LDS: (q,kv)->q*64 + (((kv>>3)^(q&7))<<3) + (kv&7)
__global__ __launch_bounds__(256) void attn_k(const __bf16* __restrict__ Q,
                                              const __bf16* __restrict__ Kb,
                                              const __bf16* __restrict__ Vt,
                                              const __bf16* __restrict__ Gate,
                                              __bf16* __restrict__ Out) {
  __shared__ __align__(16) __bf16 Ks[2][64 * 128];
  __shared__ __align__(16) __bf16 Vs[2][128 * 64];
  __shared__ __align__(16) __bf16 Ps[4][16 * 64];
  const int tid = threadIdx.x;
  const int lane = tid & 63;
  const int w = tid >> 6;
  const int fr = lane & 15;
  const int fg = lane >> 4;

  const int nwg = gridDim.x * gridDim.y;
  int wg = xcd_swizzle(blockIdx.y * gridDim.x + blockIdx.x, nwg);
  const int qb = wg % gridDim.x;   // q-block index (consecutive per XCD chunk)
  const int bh = wg / gridDim.x;
  const int q0 = qb * 64;
  const int b = bh >> 4, h = bh & 15;
  const int g = h >> 2;

  // Q fragments (already scaled)
  const size_t qrow = (size_t)(b * TT + q0 + w * 16 + fr);
  bf16x8 qf[4];
#pragma unroll
  for (int kt = 0; kt < 4; kt++)
    qf[kt] = *(const bf16x8*)&Q[qrow * 2048 + h * 128 + kt * 32 + fg * 8];

  // staging pointers (inverse-swizzled global sources)
  const __bf16* kPtr[4];
  const __bf16* vPtr[4];
#pragma unroll
  for (int i = 0; i < 4; i++) {
    int krow = w * 16 + i * 4 + (lane >> 4);               // tile row 0..63
    int kcol8 = (lane & 15) ^ (krow & 15);
    kPtr[i] = Kb + (size_t)(b * TT + krow) * 512 + g * 128 + kcol8 * 8;
    int dloc = w * 32 + i * 8 + (lane >> 3);               // d row 0..127
    int kv8 = (lane & 7) ^ (dloc & 7);
    vPtr[i] = Vt + (size_t)(g * 128 + dloc) * (size_t)MM + b * TT + kv8 * 8;
  }

  f32x4 o[8];
#pragma unroll
  for (int i = 0; i < 8; i++) o[i] = (f32x4){0.f, 0.f, 0.f, 0.f};
  float mrow[4] = {-3e38f, -3e38f, -3e38f, -3e38f};
  float lrow[4] = {0.f, 0.f, 0.f, 0.f};

  const int nsteps = qb + 1;

  // prologue stage
#pragma unroll
  for (int i = 0; i < 4; i++) {
    gload_lds16(kPtr[i], &Ks[0][w * 2048 + i * 512]);
    gload_lds16(vPtr[i], &Vs[0][w * 2048 + i * 512]);
  }
  __syncthreads();

  for (int t = 0; t < nsteps; t++) {
    const int cur = t & 1;
    const int kb = t * 64;
    if (t + 1 < nsteps) {
      const int nb = kb + 64;
#pragma unroll
      for (int i = 0; i < 4; i++) {
        gload_lds16(kPtr[i] + (size_t)nb * 512, &Ks[cur ^ 1][w * 2048 + i * 512]);
        gload_lds16(vPtr[i] + nb, &Vs[cur ^ 1][w * 2048 + i * 512]);
      }
    }

    // QK^T: 4 col-tiles x 4 k-slabs
    f32x4 s[4];
#pragma unroll
    for (int nc = 0; nc < 4; nc++) s[nc] = (f32x4){0.f, 0.f, 0.f, 0.f};
#pragma unroll
    for (int nc = 0; nc < 4; nc++)
#pragma unroll
      for (int kt = 0; kt < 4; kt++) {
        bf16x8 kf = *(const bf16x8*)&Ks[cur][(nc * 16 + fr) * 128 + (((kt * 4 + fg) ^ fr) << 3)];
        s[nc] = __builtin_amdgcn_mfma_f32_16x16x32_bf16(qf[kt], kf, s[nc], 0, 0, 0);
      }

    // online softmax
    float alpha[4];
#pragma unroll
    for (int j = 0; j < 4; j++) {
      const int qr = q0 + w * 16 + fg * 4 + j;
      float pv[4];
#pragma unroll
      for (int nc = 0; nc < 4; nc++) {
        int kc = kb + nc * 16 + fr;
        float val = s[nc][j];
        if (kc > qr) val = -1e9f;
        pv[nc] = val;
      }
      float tmx = fmaxf(fmaxf(pv[0], pv[1]), fmaxf(pv[2], pv[3]));
      tmx = fmaxf(tmx, __shfl_xor(tmx, 1, 64));
      tmx = fmaxf(tmx, __shfl_xor(tmx, 2, 64));
      tmx = fmaxf(tmx, __shfl_xor(tmx, 4, 64));
      tmx = fmaxf(tmx, __shfl_xor(tmx, 8, 64));
      float mnew = fmaxf(mrow[j], tmx);
      alpha[j] = __expf(mrow[j] - mnew);
      mrow[j] = mnew;
      float rsum = 0.f;
      const int q = fg * 4 + j;
#pragma unroll
      for (int nc = 0; nc < 4; nc++) {
        float e = __expf(pv[nc] - mnew);
        rsum += e;
        // P store (swizzled): q row, kv = nc*16+fr
        Ps[w][q * 64 + (((nc * 2 + (fr >> 3)) ^ (q & 7)) << 3) + (fr & 7)] = (__bf16)e;
      }
      rsum += __shfl_xor(rsum, 1, 64);
      rsum += __shfl_xor(rsum, 2, 64);
      rsum += __shfl_xor(rsum, 4, 64);
      rsum += __shfl_xor(rsum, 8, 64);
      lrow[j] = lrow[j] * alpha[j] + rsum;
    }
#pragma unroll
    for (int nd = 0; nd < 8; nd++)
#pragma unroll
      for (int j = 0; j < 4; j++) o[nd][j] *= alpha[j];

    // PV: A = P[q][kv], B = V[kv][d]
    bf16x8 pa[2];
#pragma unroll
    for (int sl = 0; sl < 2; sl++)
      pa[sl] = *(const bf16x8*)&Ps[w][fr * 64 + (((sl * 4 + fg) ^ (fr & 7)) << 3)];
#pragma unroll
    for (int nd = 0; nd < 8; nd++)
#pragma unroll
      for (int sl = 0; sl < 2; sl++) {
        bf16x8 vf =
            *(const bf16x8*)&Vs[cur][(nd * 16 + fr) * 64 + (((sl * 4 + fg) ^ (fr & 7)) << 3)];
        o[nd] = __builtin_amdgcn_mfma_f32_16x16x32_bf16(pa[sl], vf, o[nd], 0, 0, 0);
      }
    __syncthreads();
  }

  float invl[4];
#pragma unroll
  for (int j = 0; j < 4; j++) invl[j] = 1.0f / lrow[j];
#pragma unroll
  for (int nd = 0; nd < 8; nd++) {
#pragma unroll
    for (int j = 0; j < 4; j++) {
      int row = q0 + w * 16 + fg * 4 + j;
      int d = nd * 16 + fr;
      size_t idx = (size_t)(b * TT + row) * 2048 + h * 128 + d;
      float val = o[nd][j] * invl[j] * (float)Gate[idx];
      Out[idx] = (__bf16)val;
    }
  }
}

// ---------------- host ----------------
extern "C" void kernel_launch(void* const* d_in, const int* in_sizes, int n_in,
                              void* d_out, int out_size, void* d_ws, size_t ws_size,
                              hipStream_t stream) {
  const float* hidden = (const float*)d_in[0];
  const int* posids = (const int*)d_in[2];
  const float* attn_w = (const float*)d_in[3];
  const float* mlp_w = (const float*)d_in[4];
  const float* wq = (const float*)d_in[5];
  const float* wk = (const float*)d_in[6];
  const float* wv = (const float*)d_in[7];
  const float* wo = (const float*)d_in[8];
  const float* gw = (const float*)d_in[9];
  const float* gb = (const float*)d_in[10];
  const float* f1 = (const float*)d_in[11];
  const float* f2 = (const float*)d_in[12];

  char* p = (char*)d_ws;
  auto alloc = [&](size_t n) {
    char* r = p;
    p += (n + 255) & ~(size_t)255;
    return r;
  };
  __bf16* wq_t = (__bf16*)alloc((size_t)2048 * 2048 * 2);
  __bf16* wk_t = (__bf16*)alloc((size_t)512 * 2048 * 2);
  __bf16* wv_t = (__bf16*)alloc((size_t)512 * 2048 * 2);
  __bf16* gw_t = (__bf16*)alloc((size_t)2048 * 2048 * 2);
  __bf16* wo_t = (__bf16*)alloc((size_t)2048 * 2048 * 2);
  __bf16* f1_t = (__bf16*)alloc((size_t)NI * 2048 * 2);
  __bf16* f2_t = (__bf16*)alloc((size_t)2048 * NI * 2);
  __bf16* h_bf = (__bf16*)alloc((size_t)MM * DD * 2);
  float* h1 = (float*)alloc((size_t)MM * 2048 * 4);

  char* regionA = alloc((size_t)64 * 1024 * 1024);
  __bf16* q_bf    = (__bf16*)(regionA);
  __bf16* gate_bf = (__bf16*)(regionA + (size_t)16 * 1024 * 1024);
  __bf16* attn_g  = (__bf16*)(regionA + (size_t)32 * 1024 * 1024);
  __bf16* k_bf    = (__bf16*)(regionA + (size_t)48 * 1024 * 1024);
  __bf16* v_bf    = (__bf16*)(regionA + (size_t)52 * 1024 * 1024);
  __bf16* v_t     = (__bf16*)(regionA + (size_t)56 * 1024 * 1024);
  float*  cosT    = (float*)(regionA + (size_t)60 * 1024 * 1024);
  float*  sinT    = (float*)(regionA + (size_t)62 * 1024 * 1024);
  __bf16* mlp1    = (__bf16*)(regionA);

  rope_tables_k<<<4096, 128, 0, stream>>>(cosT, sinT);

  transpose_to_bf16_k<float><<<dim3(2048 / 32, 2048 / 32), 256, 0, stream>>>(wq, wq_t, 2048, 2048);
  transpose_to_bf16_k<float><<<dim3(512 / 32, 2048 / 32), 256, 0, stream>>>(wk, wk_t, 2048, 512);
  transpose_to_bf16_k<float><<<dim3(512 / 32, 2048 / 32), 256, 0, stream>>>(wv, wv_t, 2048, 512);
  transpose_to_bf16_k<float><<<dim3(2048 / 32, 2048 / 32), 256, 0, stream>>>(gw, gw_t, 2048, 2048);
  transpose_to_bf16_k<float><<<dim3(2048 / 32, 2048 / 32), 256, 0, stream>>>(wo, wo_t, 2048, 2048);
  transpose_to_bf16_k<float><<<dim3(NI / 32, 2048 / 32), 256, 0, stream>>>(f1, f1_t, 2048, NI);
  transpose_to_bf16_k<float><<<dim3(2048 / 32, NI / 32), 256, 0, stream>>>(f2, f2_t, NI, 2048);

  rmsnorm_k<<<MM, 256, 0, stream>>>(hidden, attn_w, h_bf);

  const float qsc = 0.08838834764831845f;  // 1/sqrt(128), folded into Q
  gemm_k<EPI_ROPE><<<dim3(16, 32), 256, 0, stream>>>(h_bf, wq_t, q_bf, nullptr, nullptr,
                                                     nullptr, cosT, sinT, posids, 2048, 2048, qsc);
  gemm_k<EPI_ROPE><<<dim3(4, 32), 256, 0, stream>>>(h_bf, wk_t, k_bf, nullptr, nullptr,
                                                    nullptr, cosT, sinT, posids, 512, 2048, 1.0f);
  gemm_k<EPI_BF16><<<dim3(4, 32), 256, 0, stream>>>(h_bf, wv_t, v_bf, nullptr, nullptr,
                                                    nullptr, nullptr, nullptr, nullptr, 512, 2048, 1.0f);
  gemm_k<EPI_SIG><<<dim3(16, 32), 256, 0, stream>>>(h_bf, gw_t, gate_bf, nullptr, gb,
                                                    nullptr, nullptr, nullptr, nullptr, 2048, 2048, 1.0f);

  transpose_to_bf16_k<__bf16><<<dim3(512 / 32, MM / 32), 256, 0, stream>>>(v_bf, v_t, MM, 512);

  attn_k<<<dim3(TT / 64, BB * NH), 256, 0, stream>>>(q_bf, k_bf, v_t, gate_bf, attn_g);

  gemm_k<EPI_RES><<<dim3(16, 32), 256, 0, stream>>>(attn_g, wo_t, nullptr, h1, nullptr,
                                                    hidden, nullptr, nullptr, nullptr, 2048, 2048, 1.0f);

  rmsnorm_k<<<MM, 256, 0, stream>>>(h1, mlp_w, h_bf);

  gemm_k<EPI_SILU><<<dim3(NI / 128, 32), 256, 0, stream>>>(h_bf, f1_t, mlp1, nullptr, nullptr,
                                                           nullptr, nullptr, nullptr, nullptr, NI, 2048, 1.0f);

  gemm_k<EPI_RES><<<dim3(16, 32), 256, 0, stream>>>(mlp1, f2_t, nullptr, (float*)d_out, nullptr,
                                                    h1, nullptr, nullptr, nullptr, 2048, NI, 1.0f);
}